// Round 17
// baseline (26.021 us; speedup 1.0000x reference)
//
#include <hip/hip_runtime.h>

// Bidirectional Chamfer loss, fused:
//   out = 1e-4 * ( sum_n min_m |shape[b,n]-skel[b,m]|^2
//                + sum_m min_n |skel[b,m]-shape[b,n]|^2 )
//
// R17: scan-structure changes R7/R10/R14/R16 all land 24.2-24.8 => the
// scan is not the cost; re-fitting R11's REP ladder puts the PROLOGUE at
// ~8-10us: 16 query points per thread at stride-256 = 48 scalar dword
// loads x ~12 cache lines each. Single change vs R14: CONTIGUOUS query
// assignment (thread owns q = tid*16..tid*16+15) -> 12 coalesced float4
// loads; stores become dense per-block. Partials layout [b][ch][q] is
// unchanged, so reduce/final remain R7-verbatim.

#define QPT    16     // query points per thread (contiguous)
#define BIGF   3.4e38f

// ws layout (floats):
//  dir1 partials [b][ch][q] : 4 x 32 x 8192 = 1,048,576
//  dir2 partials [b][ch][q] : 4 x 128 x 2048 = 1,048,576 (at P2_OFF)
//  psum: RBLOCKS floats at PSUM_OFF
#define P2_OFF   1048576
#define PSUM_OFF 2097152
#define RBLOCKS  640

__global__ __launch_bounds__(256) void chamfer_kernel(
    const float* __restrict__ shape,  // [4, 8192, 3]
    const float* __restrict__ skel,   // [4, 2048, 3]
    float* __restrict__ pw)           // partial mins
{
    const int b   = blockIdx.y;
    const int tid = threadIdx.x;

    const float* q; float* pbase; const float* ssrc;
    int q0, lbase, scount;
    int x = blockIdx.x;
    if (x < 64) {                     // dir1: shape -> skel
        const int qb = x >> 5, ch = x & 31;      // 2 qb x 32 ch
        pbase   = pw + ((size_t)b * 32 + ch) * 8192;
        q0      = qb * 4096 + tid * QPT;         // 16 contiguous queries
        lbase   = 0;  scount = 64;
        ssrc    = skel + ((size_t)b * 2048 + ch * 64) * 3;
        q       = shape + (size_t)b * 8192 * 3;
    } else {                          // dir2: skel -> shape
        const int z = x - 64, half = tid >> 7;
        const int ch = 2 * z + half;
        pbase   = pw + P2_OFF + ((size_t)b * 128 + ch) * 2048;
        q0      = (tid & 127) * QPT;             // 16 contiguous queries
        lbase   = half * 64;  scount = 128;
        ssrc    = shape + ((size_t)b * 8192 + z * 128) * 3;
        q       = skel + (size_t)b * 2048 * 3;
    }

    __shared__ float4 lds[128];

    // Stage targets as (x, y, z, |t|^2). dir1: 64, dir2: 128 (two chunks).
    if (tid < scount) {
        float tx = ssrc[tid * 3 + 0], ty = ssrc[tid * 3 + 1], tz = ssrc[tid * 3 + 2];
        lds[tid] = make_float4(tx, ty, tz, tx * tx + ty * ty + tz * tz);
    }

    // Load my 16 CONTIGUOUS query points: 48 floats = 12 coalesced float4.
    float qf[48];
    {
        const float4* qp4 = (const float4*)(q + (size_t)q0 * 3);
        #pragma unroll
        for (int v = 0; v < 12; ++v) {
            float4 t4 = qp4[v];
            qf[v * 4 + 0] = t4.x; qf[v * 4 + 1] = t4.y;
            qf[v * 4 + 2] = t4.z; qf[v * 4 + 3] = t4.w;
        }
    }
    float nqx[QPT], nqy[QPT], nqz[QPT], qsq[QPT], mn[QPT];
    #pragma unroll
    for (int k = 0; k < QPT; ++k) {
        float xq = qf[k * 3 + 0], yq = qf[k * 3 + 1], zq = qf[k * 3 + 2];
        nqx[k] = -2.0f * xq; nqy[k] = -2.0f * yq; nqz[k] = -2.0f * zq;
        qsq[k] = xq * xq + yq * yq + zq * zq;
        mn[k]  = BIGF;
    }

    __syncthreads();

    // Scan 64 targets: per 2 targets & query -> 6 FMA + 1 v_min3_f32.
    #pragma unroll 2
    for (int j = 0; j < 64; j += 2) {
        float4 ta = lds[lbase + j + 0];           // broadcast: conflict-free
        float4 tb = lds[lbase + j + 1];
        #pragma unroll
        for (int k = 0; k < QPT; ++k) {
            float e0 = fmaf(nqx[k], ta.x,
                       fmaf(nqy[k], ta.y, fmaf(nqz[k], ta.z, ta.w)));
            float e1 = fmaf(nqx[k], tb.x,
                       fmaf(nqy[k], tb.y, fmaf(nqz[k], tb.z, tb.w)));
            mn[k] = fminf(fminf(mn[k], e0), e1);  // v_min3_f32
        }
    }

    // Dense per-thread store: 4 float4 = 16 contiguous partials.
    {
        float4* ob = (float4*)(pbase + q0);
        #pragma unroll
        for (int v = 0; v < 4; ++v)
            ob[v] = make_float4(qsq[v*4+0] + mn[v*4+0], qsq[v*4+1] + mn[v*4+1],
                                qsq[v*4+2] + mn[v*4+2], qsq[v*4+3] + mn[v*4+3]);
    }
}

// 640 blocks: 64 queries/block, 4 lanes per query split over chunks.
// Blocks 0..511 = dir1 (32 chunks), 512..639 = dir2 (128 chunks).
__global__ __launch_bounds__(256) void reduce_kernel(
    const float* __restrict__ pw, float* __restrict__ psum)
{
    const int blk = blockIdx.x, tid = threadIdx.x;
    const int sub = tid & 3, qi = tid >> 2;       // 4 lanes per query

    float m = BIGF;
    if (blk < 512) {                              // dir1: 8 loads/lane
        const int b  = blk >> 7;
        const int ql = ((blk & 127) << 6) + qi;
        const float* p = pw + (size_t)b * 32 * 8192 + ql;
        #pragma unroll
        for (int i = 0; i < 8; ++i)
            m = fminf(m, p[(sub * 8 + i) * 8192]);
    } else {                                      // dir2: 32 loads/lane
        const int z  = blk - 512;
        const int b  = z >> 5;
        const int ql = ((z & 31) << 6) + qi;
        const float* p = pw + P2_OFF + (size_t)b * 128 * 2048 + ql;
        #pragma unroll
        for (int i = 0; i < 32; ++i)
            m = fminf(m, p[(sub * 32 + i) * 2048]);
    }

    // Min across the 4-lane group, clamp, keep one copy.
    m = fminf(m, __shfl_xor(m, 1));
    m = fminf(m, __shfl_xor(m, 2));
    float s = (sub == 0) ? fmaxf(m, 0.0f) : 0.0f;

    // Wave + block sum.
    #pragma unroll
    for (int off = 32; off > 0; off >>= 1)
        s += __shfl_down(s, off);

    __shared__ float wsum[4];
    const int lane = tid & 63, w = tid >> 6;
    if (lane == 0) wsum[w] = s;
    __syncthreads();
    if (tid == 0) psum[blk] = (wsum[0] + wsum[1]) + (wsum[2] + wsum[3]);
}

__global__ __launch_bounds__(256) void final_kernel(
    const float* __restrict__ psum, float* __restrict__ out)
{
    float s = psum[threadIdx.x] + psum[threadIdx.x + 256];
    if (threadIdx.x < 128) s += psum[threadIdx.x + 512];

    #pragma unroll
    for (int off = 32; off > 0; off >>= 1)
        s += __shfl_down(s, off);

    __shared__ float wsum[4];
    const int lane = threadIdx.x & 63, w = threadIdx.x >> 6;
    if (lane == 0) wsum[w] = s;
    __syncthreads();
    if (threadIdx.x == 0)
        out[0] = ((wsum[0] + wsum[1]) + (wsum[2] + wsum[3])) * 1.0e-4f;
}

extern "C" void kernel_launch(void* const* d_in, const int* in_sizes, int n_in,
                              void* d_out, int out_size, void* d_ws, size_t ws_size,
                              hipStream_t stream) {
    const float* shape = (const float*)d_in[0];   // [4, 8192, 3]
    const float* skel  = (const float*)d_in[1];   // [4, 2048, 3]
    float* out         = (float*)d_out;           // scalar f32
    float* pw          = (float*)d_ws;

    // 128 tiles/batch x 4 batches = 512 blocks (2/CU, 8 waves/CU).
    chamfer_kernel<<<dim3(128, 4), 256, 0, stream>>>(shape, skel, pw);

    // 640 blocks, then tiny deterministic final sum.
    reduce_kernel<<<RBLOCKS, 256, 0, stream>>>(pw, pw + PSUM_OFF);
    final_kernel<<<1, 256, 0, stream>>>(pw + PSUM_OFF, out);
}